// Round 6
// baseline (117.667 us; speedup 1.0000x reference)
//
#include <hip/hip_runtime.h>

#define NB_CAT  8192
#define RANK    16
#define N_COLS  4
#define N_PAIRS 1048576

#define SLICES      (N_COLS * 2)                   // (col, rank-half)
#define SLICE_BYTES (NB_CAT * 16)                  // 8192 rows x 16 B (8 fp16) = 128 KB
#define TBL_BYTES   ((size_t)SLICES * SLICE_BYTES) // 1 MB
#define IDX_BYTES   ((size_t)N_PAIRS * N_COLS * 4) // 16 MB per array
#define WS_FULL     (TBL_BYTES + 2 * IDX_BYTES)    // table + xT + yT = 33 MB

typedef _Float16 half2_t __attribute__((ext_vector_type(2)));

#if defined(__has_builtin)
#if __has_builtin(__builtin_amdgcn_fdot2)
#define HAVE_FDOT2 1
#endif
#endif

__device__ __forceinline__ float dot8_f16(uint4 A, uint4 B, float acc) {
#ifdef HAVE_FDOT2
    acc = __builtin_amdgcn_fdot2(__builtin_bit_cast(half2_t, A.x), __builtin_bit_cast(half2_t, B.x), acc, false);
    acc = __builtin_amdgcn_fdot2(__builtin_bit_cast(half2_t, A.y), __builtin_bit_cast(half2_t, B.y), acc, false);
    acc = __builtin_amdgcn_fdot2(__builtin_bit_cast(half2_t, A.z), __builtin_bit_cast(half2_t, B.z), acc, false);
    acc = __builtin_amdgcn_fdot2(__builtin_bit_cast(half2_t, A.w), __builtin_bit_cast(half2_t, B.w), acc, false);
#else
    half2_t ax = __builtin_bit_cast(half2_t, A.x), bx = __builtin_bit_cast(half2_t, B.x);
    half2_t ay = __builtin_bit_cast(half2_t, A.y), by = __builtin_bit_cast(half2_t, B.y);
    half2_t az = __builtin_bit_cast(half2_t, A.z), bz = __builtin_bit_cast(half2_t, B.z);
    half2_t aw = __builtin_bit_cast(half2_t, A.w), bw = __builtin_bit_cast(half2_t, B.w);
    acc = fmaf((float)ax[0], (float)bx[0], acc); acc = fmaf((float)ax[1], (float)bx[1], acc);
    acc = fmaf((float)ay[0], (float)by[0], acc); acc = fmaf((float)ay[1], (float)by[1], acc);
    acc = fmaf((float)az[0], (float)bz[0], acc); acc = fmaf((float)az[1], (float)bz[1], acc);
    acc = fmaf((float)aw[0], (float)bw[0], acc); acc = fmaf((float)aw[1], (float)bw[1], acc);
#endif
    return acc;
}

// ---------- prep 1: fp32 cf -> fp16 table, layout [slice=(c,h)][cat] row=16 B ----------
__global__ __launch_bounds__(256) void pack_f16_kernel(
    const float4* __restrict__ src, uint4* __restrict__ dst)
{
    const int g = blockIdx.x * 256 + threadIdx.x;   // slice*8192 + cat
    const int s = g >> 13;
    const int k = g & (NB_CAT - 1);
    const int c = s >> 1, h = s & 1;

    const float4 f0 = src[(c * NB_CAT + k) * 4 + h * 2];
    const float4 f1 = src[(c * NB_CAT + k) * 4 + h * 2 + 1];

    half2_t p0 = {(_Float16)f0.x, (_Float16)f0.y};
    half2_t p1 = {(_Float16)f0.z, (_Float16)f0.w};
    half2_t p2 = {(_Float16)f1.x, (_Float16)f1.y};
    half2_t p3 = {(_Float16)f1.z, (_Float16)f1.w};

    uint4 u;
    u.x = __builtin_bit_cast(unsigned int, p0);
    u.y = __builtin_bit_cast(unsigned int, p1);
    u.z = __builtin_bit_cast(unsigned int, p2);
    u.w = __builtin_bit_cast(unsigned int, p3);
    dst[g] = u;
}

// ---------- prep 2 (optional): transpose indices (P,4) -> (4,P) for coalesced col reads ----------
__global__ __launch_bounds__(256) void transpose_idx_kernel(
    const int4* __restrict__ x4, const int4* __restrict__ y4,
    int* __restrict__ xT, int* __restrict__ yT)
{
    const int p = blockIdx.x * 256 + threadIdx.x;
    const int4 a = x4[p];
    const int4 b = y4[p];
    xT[0 * N_PAIRS + p] = a.x; xT[1 * N_PAIRS + p] = a.y;
    xT[2 * N_PAIRS + p] = a.z; xT[3 * N_PAIRS + p] = a.w;
    yT[0 * N_PAIRS + p] = b.x; yT[1 * N_PAIRS + p] = b.y;
    yT[2 * N_PAIRS + p] = b.z; yT[3 * N_PAIRS + p] = b.w;
}

// ---------- prep 3: zero the output (it is re-poisoned 0xAA before every replay) ----------
__global__ __launch_bounds__(256) void zero_out_kernel(float4* __restrict__ out) {
    out[blockIdx.x * 256 + threadIdx.x] = float4{0.f, 0.f, 0.f, 0.f};
}

// ---------- main: slice-resident blocks, stage once, no phase barriers ----------
// 256 blocks x 1024 threads. blockIdx = slice*32 + chunk. Each block stages its
// 128 KB slice once, then streams 32768 pairs (32/thread), ds_read_b128 x2 +
// 4 fdot2 per pair, atomicAdd f32 partial into out[p] (8 partials per output).
__global__ __launch_bounds__(1024, 1) void IndexKernel_32238024524411_kernel(
    const int*   __restrict__ xs,    // index array (layout per ps/cs)
    const int*   __restrict__ ys,
    int ps, int cs,                  // element addr = p*ps + c*cs
    const uint4* __restrict__ tbl,   // fp16 table in ws
    const float* __restrict__ stdv,  // (N_COLS, NB_CAT) fp32
    float*       __restrict__ out)
{
    extern __shared__ uint4 sh[];    // 8192 rows = 128 KB

    const int tid   = threadIdx.x;
    const int slice = blockIdx.x >> 5;    // 0..7
    const int chunk = blockIdx.x & 31;    // 0..31
    const int c     = slice >> 1;
    const int h     = slice & 1;

    // one-time stage of this block's slice
    const uint4* src = tbl + slice * NB_CAT;
#pragma unroll
    for (int it = 0; it < 8; ++it) {
        sh[tid + it * 1024] = src[tid + it * 1024];
    }
    __syncthreads();

    const int pbase = chunk * 32768 + tid;
    const int cb    = c * cs;

#pragma unroll
    for (int g = 0; g < 4; ++g) {
        int xi[8], yi[8];
#pragma unroll
        for (int j = 0; j < 8; ++j) {
            const int p = pbase + (g * 8 + j) * 1024;
            xi[j] = xs[p * ps + cb];
            yi[j] = ys[p * ps + cb];
        }
#pragma unroll
        for (int j = 0; j < 8; ++j) {
            const int p = pbase + (g * 8 + j) * 1024;
            const uint4 ax = sh[xi[j]];
            const uint4 ay = sh[yi[j]];
            float d = dot8_f16(ax, ay, 0.f);
            if (h == 0 && xi[j] == yi[j]) {
                const float sd = stdv[c * NB_CAT + xi[j]];
                d = fmaf(sd, sd, d);
            }
            unsafeAtomicAdd(&out[p], d);   // native global_atomic_add_f32
        }
    }
}

// ---------- fallback (fp32 direct gather, R3 structure) if ws too small ----------
__global__ __launch_bounds__(256) void fallback_kernel(
    const int* __restrict__ x, const int* __restrict__ y,
    const float4* __restrict__ cf, const float* __restrict__ stdv,
    float* __restrict__ out)
{
    const int tid = threadIdx.x;
    const int q = tid & 15, gi = tid >> 4, c = q >> 2, s = q & 3;
    const int p0 = blockIdx.x * 32 + gi, p1 = p0 + 16;
    const int rb = c * NB_CAT;
    const int xi0 = x[p0*4+c], yi0 = y[p0*4+c], xi1 = x[p1*4+c], yi1 = y[p1*4+c];
    const float4 a0 = cf[(size_t)(rb+xi0)*4 + s], b0 = cf[(size_t)(rb+yi0)*4 + s];
    const float4 a1 = cf[(size_t)(rb+xi1)*4 + s], b1 = cf[(size_t)(rb+yi1)*4 + s];
    float v0 = a0.x*b0.x; v0 = fmaf(a0.y,b0.y,v0); v0 = fmaf(a0.z,b0.z,v0); v0 = fmaf(a0.w,b0.w,v0);
    float v1 = a1.x*b1.x; v1 = fmaf(a1.y,b1.y,v1); v1 = fmaf(a1.z,b1.z,v1); v1 = fmaf(a1.w,b1.w,v1);
    if (s == 0 && xi0 == yi0) { float sd = stdv[rb+xi0]; v0 = fmaf(sd,sd,v0); }
    if (s == 0 && xi1 == yi1) { float sd = stdv[rb+yi1]; v1 = fmaf(sd,sd,v1); }
    int t;
    t = __builtin_amdgcn_update_dpp(0, __float_as_int(v0), 0xB1, 0xF, 0xF, true); v0 += __int_as_float(t);
    t = __builtin_amdgcn_update_dpp(0, __float_as_int(v0), 0x4E, 0xF, 0xF, true); v0 += __int_as_float(t);
    t = __builtin_amdgcn_update_dpp(0, __float_as_int(v0), 0x141,0xF, 0xF, true); v0 += __int_as_float(t);
    t = __builtin_amdgcn_update_dpp(0, __float_as_int(v0), 0x128,0xF, 0xF, true); v0 += __int_as_float(t);
    t = __builtin_amdgcn_update_dpp(0, __float_as_int(v1), 0xB1, 0xF, 0xF, true); v1 += __int_as_float(t);
    t = __builtin_amdgcn_update_dpp(0, __float_as_int(v1), 0x4E, 0xF, 0xF, true); v1 += __int_as_float(t);
    t = __builtin_amdgcn_update_dpp(0, __float_as_int(v1), 0x141,0xF, 0xF, true); v1 += __int_as_float(t);
    t = __builtin_amdgcn_update_dpp(0, __float_as_int(v1), 0x128,0xF, 0xF, true); v1 += __int_as_float(t);
    if (q == 0) { out[p0] = v0; out[p1] = v1; }
}

extern "C" void kernel_launch(void* const* d_in, const int* in_sizes, int n_in,
                              void* d_out, int out_size, void* d_ws, size_t ws_size,
                              hipStream_t stream) {
    const int*   x    = (const int*)d_in[0];
    const int*   y    = (const int*)d_in[1];
    const float* cf   = (const float*)d_in[2];
    const float* stdv = (const float*)d_in[3];
    float*       out  = (float*)d_out;

    if (ws_size < TBL_BYTES) {
        fallback_kernel<<<N_PAIRS / 32, 256, 0, stream>>>(
            x, y, (const float4*)cf, stdv, out);
        return;
    }

    (void)hipFuncSetAttribute(
        reinterpret_cast<const void*>(&IndexKernel_32238024524411_kernel),
        hipFuncAttributeMaxDynamicSharedMemorySize, SLICE_BYTES);

    pack_f16_kernel<<<SLICES * NB_CAT / 256, 256, 0, stream>>>(
        (const float4*)cf, (uint4*)d_ws);
    zero_out_kernel<<<N_PAIRS / 4 / 256, 256, 0, stream>>>((float4*)out);

    const int* xs = x;
    const int* ys = y;
    int ps = N_COLS, cs = 1;
    if (ws_size >= WS_FULL) {
        int* xT = (int*)((char*)d_ws + TBL_BYTES);
        int* yT = xT + (size_t)N_COLS * N_PAIRS;
        transpose_idx_kernel<<<N_PAIRS / 256, 256, 0, stream>>>(
            (const int4*)x, (const int4*)y, xT, yT);
        xs = xT; ys = yT; ps = 1; cs = N_PAIRS;
    }

    IndexKernel_32238024524411_kernel<<<SLICES * 32, 1024, SLICE_BYTES, stream>>>(
        xs, ys, ps, cs, (const uint4*)d_ws, stdv, out);
}

// Round 7
// 96.990 us; speedup vs baseline: 1.2132x; 1.2132x over previous
//
#include <hip/hip_runtime.h>

#define NB_CAT  8192
#define RANK    16
#define N_COLS  4
#define N_PAIRS 1048576

#define NSLICE      16                        // (col, rank-quarter)
#define SLICE_ROWS  NB_CAT                    // rows of 8 B (4 fp16)
#define SLICE_BYTES (SLICE_ROWS * 8)          // 64 KB
#define TBL_BYTES   ((size_t)NSLICE * SLICE_BYTES)  // 1 MB
#define LDS_BYTES   (2 * SLICE_BYTES)         // 128 KB (double buffer)

typedef _Float16 half2_t __attribute__((ext_vector_type(2)));

#if defined(__has_builtin)
#if __has_builtin(__builtin_amdgcn_fdot2)
#define HAVE_FDOT2 1
#endif
#endif

__device__ __forceinline__ float dot4_f16(uint2 A, uint2 B, float acc) {
#ifdef HAVE_FDOT2
    acc = __builtin_amdgcn_fdot2(__builtin_bit_cast(half2_t, A.x), __builtin_bit_cast(half2_t, B.x), acc, false);
    acc = __builtin_amdgcn_fdot2(__builtin_bit_cast(half2_t, A.y), __builtin_bit_cast(half2_t, B.y), acc, false);
#else
    half2_t ax = __builtin_bit_cast(half2_t, A.x), bx = __builtin_bit_cast(half2_t, B.x);
    half2_t ay = __builtin_bit_cast(half2_t, A.y), by = __builtin_bit_cast(half2_t, B.y);
    acc = fmaf((float)ax[0], (float)bx[0], acc); acc = fmaf((float)ax[1], (float)bx[1], acc);
    acc = fmaf((float)ay[0], (float)by[0], acc); acc = fmaf((float)ay[1], (float)by[1], acc);
#endif
    return acc;
}

template <int C> __device__ __forceinline__ int comp(const int4& v) {
    if (C == 0) return v.x;
    if (C == 1) return v.y;
    if (C == 2) return v.z;
    return v.w;
}

// ---------- prep: fp32 cf -> fp16 table, layout [slice=(c,qr)][cat] row = 8 B ----------
__global__ __launch_bounds__(256) void pack_f16_kernel(
    const float4* __restrict__ src, uint2* __restrict__ dst)
{
    const int g = blockIdx.x * 256 + threadIdx.x;   // slice*8192 + cat, 131072 total
    const int s = g >> 13;
    const int k = g & (NB_CAT - 1);
    const int c = s >> 2, qr = s & 3;

    const float4 f = src[(c * NB_CAT + k) * 4 + qr];
    half2_t p0 = {(_Float16)f.x, (_Float16)f.y};
    half2_t p1 = {(_Float16)f.z, (_Float16)f.w};
    uint2 u;
    u.x = __builtin_bit_cast(unsigned int, p0);
    u.y = __builtin_bit_cast(unsigned int, p1);
    dst[g] = u;
}

// ---------- main: phase loop with software-pipelined double-buffered staging ----------
// 256 blocks x 1024 threads, 128 KB dyn LDS (2 x 64 KB). 16 phases; each phase:
// ds_write slice s (from regs), issue global prefetch of slice s+1 (stays in
// flight ACROSS the raw barrier), lgkm-only barrier, gather-compute slice s.
__global__ __launch_bounds__(1024, 1) void IndexKernel_32238024524411_kernel(
    const int4*  __restrict__ x4,    // (N_PAIRS) int4
    const int4*  __restrict__ y4,
    const uint2* __restrict__ tbl,   // fp16 table in ws
    const float* __restrict__ stdv,  // (N_COLS, NB_CAT) fp32
    float*       __restrict__ out)
{
    extern __shared__ uint2 sh[];    // 2 * SLICE_ROWS

    const int tid  = threadIdx.x;
    const int base = blockIdx.x * 4096 + tid;

    // coalesced one-time index loads (held in registers for all phases)
    int4 xv[4], yv[4];
#pragma unroll
    for (int j = 0; j < 4; ++j) {
        xv[j] = x4[base + j * 1024];
        yv[j] = y4[base + j * 1024];
    }

    float acc[4] = {0.f, 0.f, 0.f, 0.f};

    // preload slice 0 into staging registers
    uint2 stg[8];
#pragma unroll
    for (int it = 0; it < 8; ++it) stg[it] = tbl[tid + it * 1024];

#define PHASE(S)                                                               \
    {                                                                          \
        constexpr int s  = (S);                                                \
        constexpr int c  = s >> 2;                                             \
        constexpr int qr = s & 3;                                              \
        uint2* buf = sh + (s & 1) * SLICE_ROWS;                                \
        _Pragma("unroll")                                                      \
        for (int it = 0; it < 8; ++it) buf[tid + it * 1024] = stg[it];         \
        if (s < NSLICE - 1) {                                                  \
            const uint2* nsrc = tbl + (size_t)(s + 1) * SLICE_ROWS;            \
            _Pragma("unroll")                                                  \
            for (int it = 0; it < 8; ++it) stg[it] = nsrc[tid + it * 1024];    \
        }                                                                      \
        /* raw barrier: wait LDS writes only; prefetch stays in flight */      \
        asm volatile("s_waitcnt lgkmcnt(0)" ::: "memory");                     \
        __builtin_amdgcn_s_barrier();                                          \
        asm volatile("" ::: "memory");                                         \
        _Pragma("unroll")                                                      \
        for (int j = 0; j < 4; ++j) {                                          \
            const int xi = comp<c>(xv[j]);                                     \
            const int yi = comp<c>(yv[j]);                                     \
            const uint2 a = buf[xi];                                           \
            const uint2 b = buf[yi];                                           \
            acc[j] = dot4_f16(a, b, acc[j]);                                   \
            if (qr == 0 && xi == yi) {                                         \
                const float sd = stdv[c * NB_CAT + xi];                        \
                acc[j] = fmaf(sd, sd, acc[j]);                                 \
            }                                                                  \
        }                                                                      \
        asm volatile("" ::: "memory");                                         \
    }

    PHASE(0)  PHASE(1)  PHASE(2)  PHASE(3)
    PHASE(4)  PHASE(5)  PHASE(6)  PHASE(7)
    PHASE(8)  PHASE(9)  PHASE(10) PHASE(11)
    PHASE(12) PHASE(13) PHASE(14) PHASE(15)
#undef PHASE

#pragma unroll
    for (int j = 0; j < 4; ++j) {
        out[base + j * 1024] = acc[j];
    }
}

// ---------- fallback (fp32 direct gather, R3 structure) if ws too small ----------
__global__ __launch_bounds__(256) void fallback_kernel(
    const int* __restrict__ x, const int* __restrict__ y,
    const float4* __restrict__ cf, const float* __restrict__ stdv,
    float* __restrict__ out)
{
    const int tid = threadIdx.x;
    const int q = tid & 15, gi = tid >> 4, c = q >> 2, s = q & 3;
    const int p0 = blockIdx.x * 32 + gi, p1 = p0 + 16;
    const int rb = c * NB_CAT;
    const int xi0 = x[p0*4+c], yi0 = y[p0*4+c], xi1 = x[p1*4+c], yi1 = y[p1*4+c];
    const float4 a0 = cf[(size_t)(rb+xi0)*4 + s], b0 = cf[(size_t)(rb+yi0)*4 + s];
    const float4 a1 = cf[(size_t)(rb+xi1)*4 + s], b1 = cf[(size_t)(rb+yi1)*4 + s];
    float v0 = a0.x*b0.x; v0 = fmaf(a0.y,b0.y,v0); v0 = fmaf(a0.z,b0.z,v0); v0 = fmaf(a0.w,b0.w,v0);
    float v1 = a1.x*b1.x; v1 = fmaf(a1.y,b1.y,v1); v1 = fmaf(a1.z,b1.z,v1); v1 = fmaf(a1.w,b1.w,v1);
    if (s == 0 && xi0 == yi0) { float sd = stdv[rb+xi0]; v0 = fmaf(sd,sd,v0); }
    if (s == 0 && xi1 == yi1) { float sd = stdv[rb+yi1]; v1 = fmaf(sd,sd,v1); }
    int t;
    t = __builtin_amdgcn_update_dpp(0, __float_as_int(v0), 0xB1, 0xF, 0xF, true); v0 += __int_as_float(t);
    t = __builtin_amdgcn_update_dpp(0, __float_as_int(v0), 0x4E, 0xF, 0xF, true); v0 += __int_as_float(t);
    t = __builtin_amdgcn_update_dpp(0, __float_as_int(v0), 0x141,0xF, 0xF, true); v0 += __int_as_float(t);
    t = __builtin_amdgcn_update_dpp(0, __float_as_int(v0), 0x128,0xF, 0xF, true); v0 += __int_as_float(t);
    t = __builtin_amdgcn_update_dpp(0, __float_as_int(v1), 0xB1, 0xF, 0xF, true); v1 += __int_as_float(t);
    t = __builtin_amdgcn_update_dpp(0, __float_as_int(v1), 0x4E, 0xF, 0xF, true); v1 += __int_as_float(t);
    t = __builtin_amdgcn_update_dpp(0, __float_as_int(v1), 0x141,0xF, 0xF, true); v1 += __int_as_float(t);
    t = __builtin_amdgcn_update_dpp(0, __float_as_int(v1), 0x128,0xF, 0xF, true); v1 += __int_as_float(t);
    if (q == 0) { out[p0] = v0; out[p1] = v1; }
}

extern "C" void kernel_launch(void* const* d_in, const int* in_sizes, int n_in,
                              void* d_out, int out_size, void* d_ws, size_t ws_size,
                              hipStream_t stream) {
    const int*   x    = (const int*)d_in[0];
    const int*   y    = (const int*)d_in[1];
    const float* cf   = (const float*)d_in[2];
    const float* stdv = (const float*)d_in[3];
    float*       out  = (float*)d_out;

    if (ws_size < TBL_BYTES) {
        fallback_kernel<<<N_PAIRS / 32, 256, 0, stream>>>(
            x, y, (const float4*)cf, stdv, out);
        return;
    }

    (void)hipFuncSetAttribute(
        reinterpret_cast<const void*>(&IndexKernel_32238024524411_kernel),
        hipFuncAttributeMaxDynamicSharedMemorySize, LDS_BYTES);

    pack_f16_kernel<<<NSLICE * NB_CAT / 256, 256, 0, stream>>>(
        (const float4*)cf, (uint2*)d_ws);

    IndexKernel_32238024524411_kernel<<<N_PAIRS / 4096, 1024, LDS_BYTES, stream>>>(
        (const int4*)x, (const int4*)y, (const uint2*)d_ws, stdv, out);
}